// Round 18
// baseline (875.911 us; speedup 1.0000x reference)
//
#include <hip/hip_runtime.h>

#define H 22
#define EPS 1e-5f
#define SLOPE 0.01f
#define NT 256
#define NBLK 1024
#define WPB 4
#define NWAVES (NBLK * WPB)

// stats accumulators: 16 contention-split slots per stage.
// block b adds into slot (b & 15): su at [0..21], sq at [32..53].
#define NSLOT 16
#define SLOTSZ 64
#define STAGESZ (NSLOT * SLOTSZ)  // 1024 floats per stage

typedef __attribute__((ext_vector_type(8))) _Float16 half8;
typedef __attribute__((ext_vector_type(4))) float f32x4;

#define MFMA(A, B, C) __builtin_amdgcn_mfma_f32_16x16x32_f16(A, B, C, 0, 0, 0)

__device__ __forceinline__ float leakyf(float u) { return u > 0.f ? u : SLOPE * u; }

// k/m mapping used CONSISTENTLY for all operand constructions:
// k(g,e) = 16*(e>>2) + 4*g + (e&3).  C-frag m at (tile,reg) = kmap(g, 4*tile+reg),
// so chained C->B repack is in-lane (validated rounds 8-17, absmax ~0.13).
__device__ __forceinline__ int kmap(int g, int e) {
  return ((e >> 2) << 4) + (g << 2) + (e & 3);
}

__device__ __forceinline__ half8 buildA(const float* __restrict__ W, int rows, int cols,
                                        int mbase, int kbase, int g) {
  int m = mbase + ((int)threadIdx.x & 15);
  half8 a;
#pragma unroll
  for (int e = 0; e < 8; e++) {
    int k = kbase + kmap(g, e);
    float v = (m < rows && k < cols) ? W[m * cols + k] : 0.f;
    a[e] = (_Float16)v;
  }
  return a;
}

// sum the 16 slots of a stage for feature t (t < H)
__device__ __forceinline__ void read_stats(const float* __restrict__ accStage,
                                           int t, float& su, float& sq) {
  su = 0.f; sq = 0.f;
#pragma unroll
  for (int sI = 0; sI < NSLOT; sI++) {
    su += accStage[sI * SLOTSZ + t];
    sq += accStage[sI * SLOTSZ + 32 + t];
  }
}

// per-wave stats -> block reduce -> 44 atomics into this block's slot
__device__ __forceinline__ void commit_stats(float* s, float* q,
                                             float red[WPB][2 * H],
                                             float* __restrict__ accStage) {
  int lane = (int)threadIdx.x & 63, w = (int)threadIdx.x >> 6, g = lane >> 4;
#pragma unroll
  for (int r = 0; r < 8; r++) {
#pragma unroll
    for (int off = 1; off < 16; off <<= 1) {
      s[r] += __shfl_xor(s[r], off);
      q[r] += __shfl_xor(q[r], off);
    }
  }
  if ((lane & 15) == 0) {
#pragma unroll
    for (int r = 0; r < 8; r++) {
      int m = kmap(g, r);
      if (m < H) { red[w][m] = s[r]; red[w][H + m] = q[r]; }
    }
  }
  __syncthreads();
  int tid = threadIdx.x;
  if (tid < 2 * H) {
    float v = red[0][tid] + red[1][tid] + red[2][tid] + red[3][tid];
    float* slot = accStage + (blockIdx.x & (NSLOT - 1)) * SLOTSZ;
    int off = (tid < H) ? tid : (32 + tid - H);
    atomicAdd(&slot[off], v);
  }
}

// ---- proj: z0 = Wp @ x + bp -> bufT (f16 frag layout), stats(z0) -> stage 0
__global__ void __launch_bounds__(NT) proj_kernel(
    const float* __restrict__ x, const float* __restrict__ Wp,
    const float* __restrict__ bp, half8* __restrict__ bufT,
    float* __restrict__ acc0, int ntiles) {
  __shared__ float sBP[32];
  __shared__ float red[WPB][2 * H];
  int tid = threadIdx.x;
  if (tid < 32) sBP[tid] = (tid < H) ? bp[tid] : 0.f;
  __syncthreads();
  int lane = tid & 63, w = tid >> 6, g = lane >> 4, n = lane & 15;
  int wid = blockIdx.x * WPB + w;

  half8 A00 = buildA(Wp, H, 64, 0, 0, g);
  half8 A01 = buildA(Wp, H, 64, 0, 32, g);
  half8 A10 = buildA(Wp, H, 64, 16, 0, g);
  half8 A11 = buildA(Wp, H, 64, 16, 32, g);
  float bpv[8];
#pragma unroll
  for (int e = 0; e < 8; e++) bpv[e] = sBP[kmap(g, e)];

  float s[8], q[8];
#pragma unroll
  for (int e = 0; e < 8; e++) { s[e] = 0.f; q[e] = 0.f; }

  const float4* x4 = (const float4*)x;
  for (int t = wid; t < ntiles; t += NWAVES) {
    size_t row = (size_t)t * 16 + n;
    float4 lo0 = x4[row * 16 + g];        // k = 4g..4g+3
    float4 hi0 = x4[row * 16 + 4 + g];    // k = 16+4g..
    float4 lo1 = x4[row * 16 + 8 + g];    // k = 32+4g..
    float4 hi1 = x4[row * 16 + 12 + g];   // k = 48+4g..
    half8 B0, B1;
    B0[0] = (_Float16)lo0.x; B0[1] = (_Float16)lo0.y;
    B0[2] = (_Float16)lo0.z; B0[3] = (_Float16)lo0.w;
    B0[4] = (_Float16)hi0.x; B0[5] = (_Float16)hi0.y;
    B0[6] = (_Float16)hi0.z; B0[7] = (_Float16)hi0.w;
    B1[0] = (_Float16)lo1.x; B1[1] = (_Float16)lo1.y;
    B1[2] = (_Float16)lo1.z; B1[3] = (_Float16)lo1.w;
    B1[4] = (_Float16)hi1.x; B1[5] = (_Float16)hi1.y;
    B1[6] = (_Float16)hi1.z; B1[7] = (_Float16)hi1.w;

    f32x4 c0 = {0.f, 0.f, 0.f, 0.f}, c1 = {0.f, 0.f, 0.f, 0.f};
    c0 = MFMA(A00, B0, c0); c0 = MFMA(A01, B1, c0);
    c1 = MFMA(A10, B0, c1); c1 = MFMA(A11, B1, c1);

    half8 zb;
#pragma unroll
    for (int e = 0; e < 8; e++) {
      float z = ((e < 4) ? c0[e & 3] : c1[e & 3]) + bpv[e];  // m>=22: A rows 0, bpv 0 -> z=0
      s[e] += z; q[e] += z * z;
      zb[e] = (_Float16)z;
    }
    bufT[(size_t)t * 64 + g * 16 + n] = zb;
  }
  commit_stats(s, q, red, acc0);
}

// ---- bn0: h0 = a0*z0 + c0 (in place) ; stats of z1_0 = W1 h0 + b1
__global__ void __launch_bounds__(NT) bn0_kernel(
    half8* __restrict__ bufT, const float* __restrict__ accIn,
    float* __restrict__ accOut, const float* __restrict__ g0,
    const float* __restrict__ be0, const float* __restrict__ W1,
    const float* __restrict__ b1, int ntiles, float invN) {
  __shared__ float sA[32], sC[32], sB1[32];
  __shared__ float red[WPB][2 * H];
  int tid = threadIdx.x;
  if (tid < 32) {
    float a = 0.f, c = 0.f, bv = 0.f;
    if (tid < H) {
      float su, sq; read_stats(accIn, tid, su, sq);
      float mu = su * invN;
      float var = sq * invN - mu * mu;
      a = g0[tid] * rsqrtf(var + EPS);
      c = be0[tid] - a * mu;
      bv = b1[tid];
    }
    sA[tid] = a; sC[tid] = c; sB1[tid] = bv;
  }
  __syncthreads();
  int lane = tid & 63, w = tid >> 6, g = lane >> 4, n = lane & 15;
  int wid = blockIdx.x * WPB + w;
  int base = g * 16 + n;

  half8 A0 = buildA(W1, H, H, 0, 0, g), A1 = buildA(W1, H, H, 16, 0, g);
  float aK[8], cK[8], b1v[8];
#pragma unroll
  for (int e = 0; e < 8; e++) {
    int m = kmap(g, e);
    aK[e] = sA[m]; cK[e] = sC[m]; b1v[e] = sB1[m];
  }
  float s[8], q[8];
#pragma unroll
  for (int e = 0; e < 8; e++) { s[e] = 0.f; q[e] = 0.f; }

  // 1-deep prefetch: next load in flight during this tile's MFMA chain.
  // Prefetched tile is this wave's own future tile (not yet written) -> reads old z, correct.
  half8 cur = bufT[(size_t)wid * 64 + base];
  for (int t = wid; t < ntiles; t += NWAVES) {
    int tn = t + NWAVES;
    half8 nxt = bufT[(size_t)(tn < ntiles ? tn : t) * 64 + base];
    half8 hb;
#pragma unroll
    for (int e = 0; e < 8; e++)
      hb[e] = (_Float16)(aK[e] * (float)cur[e] + cK[e]);   // pad features: aK=cK=0 -> 0
    bufT[(size_t)t * 64 + base] = hb;
    f32x4 c0 = {0.f, 0.f, 0.f, 0.f}, c1 = {0.f, 0.f, 0.f, 0.f};
    c0 = MFMA(A0, hb, c0);
    c1 = MFMA(A1, hb, c1);
#pragma unroll
    for (int e = 0; e < 8; e++) {
      float z = ((e < 4) ? c0[e & 3] : c1[e & 3]) + b1v[e];
      s[e] += z; q[e] += z * z;
    }
    cur = nxt;
  }
  commit_stats(s, q, red, accOut);
}

// ---- P2: t = leaky(a1*(W1 h) + b1f) ; z2 = W2 t + b2 (raw) ; stats(z2)
__global__ void __launch_bounds__(NT) p2_kernel(
    const half8* __restrict__ bufT, const float* __restrict__ accIn,
    float* __restrict__ accOut, const float* __restrict__ g1,
    const float* __restrict__ be1, const float* __restrict__ W1,
    const float* __restrict__ b1, const float* __restrict__ W2,
    const float* __restrict__ b2, int ntiles, float invN) {
  __shared__ float sA1[32], sB1F[32], sB2[32];
  __shared__ float red[WPB][2 * H];
  int tid = threadIdx.x;
  if (tid < 32) {
    float a = 0.f, bf = 0.f, bv = 0.f;
    if (tid < H) {
      float su, sq; read_stats(accIn, tid, su, sq);
      float mu = su * invN;
      float var = sq * invN - mu * mu;
      a = g1[tid] * rsqrtf(var + EPS);
      bf = a * b1[tid] + be1[tid] - a * mu;
      bv = b2[tid];
    }
    sA1[tid] = a; sB1F[tid] = bf; sB2[tid] = bv;
  }
  __syncthreads();
  int lane = tid & 63, w = tid >> 6, g = lane >> 4, n = lane & 15;
  int wid = blockIdx.x * WPB + w;
  int base = g * 16 + n;

  half8 A10 = buildA(W1, H, H, 0, 0, g), A11 = buildA(W1, H, H, 16, 0, g);
  half8 A20 = buildA(W2, H, H, 0, 0, g), A21 = buildA(W2, H, H, 16, 0, g);
  float a1v[8], b1v[8], b2v[8];
#pragma unroll
  for (int e = 0; e < 8; e++) {
    int m = kmap(g, e);
    a1v[e] = sA1[m]; b1v[e] = sB1F[m]; b2v[e] = sB2[m];
  }
  float s[8], q[8];
#pragma unroll
  for (int e = 0; e < 8; e++) { s[e] = 0.f; q[e] = 0.f; }

  half8 cur = bufT[(size_t)wid * 64 + base];
  for (int t = wid; t < ntiles; t += NWAVES) {
    int tn = t + NWAVES;
    half8 nxt = bufT[(size_t)(tn < ntiles ? tn : t) * 64 + base];
    f32x4 c0 = {0.f, 0.f, 0.f, 0.f}, c1 = {0.f, 0.f, 0.f, 0.f};
    c0 = MFMA(A10, cur, c0);
    c1 = MFMA(A11, cur, c1);
    half8 tb;
#pragma unroll
    for (int e = 0; e < 8; e++) {
      float c = (e < 4) ? c0[e & 3] : c1[e & 3];
      tb[e] = (_Float16)leakyf(a1v[e] * c + b1v[e]);      // pad: a1v=b1v=0 -> 0
    }
    f32x4 d0 = {0.f, 0.f, 0.f, 0.f}, d1 = {0.f, 0.f, 0.f, 0.f};
    d0 = MFMA(A20, tb, d0);
    d1 = MFMA(A21, tb, d1);
#pragma unroll
    for (int e = 0; e < 8; e++) {
      float z = ((e < 4) ? d0[e & 3] : d1[e & 3]) + b2v[e];
      s[e] += z; q[e] += z * z;
    }
    cur = nxt;
  }
  commit_stats(s, q, red, accOut);
}

// ---- P3: recompute t, z2 ; h' = leaky(h + a2*(W2 t) + b2f) ; store h' ;
//          fused next-layer z1 stats (raw) or final output when LAST
template <int LAST>
__global__ void __launch_bounds__(NT) p3_kernel(
    half8* __restrict__ bufT, const float* __restrict__ accZ1,
    const float* __restrict__ accZ2, float* __restrict__ accOut,
    const float* __restrict__ g1, const float* __restrict__ be1,
    const float* __restrict__ g2, const float* __restrict__ be2,
    const float* __restrict__ W1, const float* __restrict__ b1,
    const float* __restrict__ W2, const float* __restrict__ b2,
    const float* __restrict__ W1n, const float* __restrict__ b1n,
    const float* __restrict__ Wo, const float* __restrict__ bo,
    float* __restrict__ out, int ntiles, float invN) {
  __shared__ float sA1[32], sB1F[32], sA2[32], sB2F[32], sAux[32];
  __shared__ float red[WPB][2 * H];
  int tid = threadIdx.x;
  if (tid < 32) {
    float a1 = 0.f, b1f = 0.f, a2 = 0.f, b2f = 0.f, aux = 0.f;
    if (tid < H) {
      float su1, sq1; read_stats(accZ1, tid, su1, sq1);
      float mu1 = su1 * invN;
      float v1 = sq1 * invN - mu1 * mu1;
      a1 = g1[tid] * rsqrtf(v1 + EPS);
      b1f = a1 * b1[tid] + be1[tid] - a1 * mu1;
      float su2, sq2; read_stats(accZ2, tid, su2, sq2);
      float mu2 = su2 * invN;
      float v2 = sq2 * invN - mu2 * mu2;
      a2 = g2[tid] * rsqrtf(v2 + EPS);
      b2f = a2 * b2[tid] + be2[tid] - a2 * mu2;
      aux = LAST ? Wo[tid] : b1n[tid];
    }
    sA1[tid] = a1; sB1F[tid] = b1f; sA2[tid] = a2; sB2F[tid] = b2f; sAux[tid] = aux;
  }
  __syncthreads();
  int lane = tid & 63, w = tid >> 6, g = lane >> 4, n = lane & 15;
  int wid = blockIdx.x * WPB + w;
  int base = g * 16 + n;

  half8 A10 = buildA(W1, H, H, 0, 0, g), A11 = buildA(W1, H, H, 16, 0, g);
  half8 A20 = buildA(W2, H, H, 0, 0, g), A21 = buildA(W2, H, H, 16, 0, g);
  half8 An0 = {}, An1 = {};
  if (!LAST) { An0 = buildA(W1n, H, H, 0, 0, g); An1 = buildA(W1n, H, H, 16, 0, g); }
  float a1v[8], b1v[8], a2v[8], b2v[8], auxv[8];
#pragma unroll
  for (int e = 0; e < 8; e++) {
    int m = kmap(g, e);
    a1v[e] = sA1[m]; b1v[e] = sB1F[m]; a2v[e] = sA2[m]; b2v[e] = sB2F[m]; auxv[e] = sAux[m];
  }
  float s[8], q[8];
#pragma unroll
  for (int e = 0; e < 8; e++) { s[e] = 0.f; q[e] = 0.f; }
  float bo0 = LAST ? bo[0] : 0.f;

  half8 cur = bufT[(size_t)wid * 64 + base];
  for (int t = wid; t < ntiles; t += NWAVES) {
    int tn = t + NWAVES;
    half8 nxt = bufT[(size_t)(tn < ntiles ? tn : t) * 64 + base];
    f32x4 c0 = {0.f, 0.f, 0.f, 0.f}, c1 = {0.f, 0.f, 0.f, 0.f};
    c0 = MFMA(A10, cur, c0);
    c1 = MFMA(A11, cur, c1);
    half8 tb;
#pragma unroll
    for (int e = 0; e < 8; e++) {
      float c = (e < 4) ? c0[e & 3] : c1[e & 3];
      tb[e] = (_Float16)leakyf(a1v[e] * c + b1v[e]);
    }
    f32x4 d0 = {0.f, 0.f, 0.f, 0.f}, d1 = {0.f, 0.f, 0.f, 0.f};
    d0 = MFMA(A20, tb, d0);
    d1 = MFMA(A21, tb, d1);
    float hn[8];
    half8 nb;
#pragma unroll
    for (int e = 0; e < 8; e++) {
      float d = (e < 4) ? d0[e & 3] : d1[e & 3];
      // residual: C-frag m at (tile,reg)=e equals B-elem feature kmap(g,e) -> same lane/elem
      float hv = (float)cur[e];
      hn[e] = leakyf(hv + a2v[e] * d + b2v[e]);            // pad: a2v=b2v=0, hv=0 -> 0
      nb[e] = (_Float16)hn[e];
    }
    if (!LAST) {
      bufT[(size_t)t * 64 + base] = nb;
      f32x4 e0 = {0.f, 0.f, 0.f, 0.f}, e1 = {0.f, 0.f, 0.f, 0.f};
      e0 = MFMA(An0, nb, e0);
      e1 = MFMA(An1, nb, e1);
#pragma unroll
      for (int e = 0; e < 8; e++) {
        float z = ((e < 4) ? e0[e & 3] : e1[e & 3]) + auxv[e];
        s[e] += z; q[e] += z * z;
      }
    } else {
      float part = 0.f;
#pragma unroll
      for (int e = 0; e < 8; e++) part += auxv[e] * hn[e];
      part += __shfl_xor(part, 16);
      part += __shfl_xor(part, 32);
      if (lane < 16) out[(size_t)t * 16 + n] = part + bo0;
    }
    cur = nxt;
  }
  if (!LAST) commit_stats(s, q, red, accOut);
}

extern "C" void kernel_launch(void* const* d_in, const int* in_sizes, int n_in,
                              void* d_out, int out_size, void* d_ws, size_t ws_size,
                              hipStream_t stream) {
  const float* x    = (const float*)d_in[0];
  const float* Wp   = (const float*)d_in[1];
  const float* bp   = (const float*)d_in[2];
  const float* g0   = (const float*)d_in[3];
  const float* be0  = (const float*)d_in[4];
  const float* W1s  = (const float*)d_in[5];
  const float* b1s  = (const float*)d_in[6];
  const float* g1s  = (const float*)d_in[7];
  const float* be1s = (const float*)d_in[8];
  const float* W2s  = (const float*)d_in[9];
  const float* b2s  = (const float*)d_in[10];
  const float* g2s  = (const float*)d_in[11];
  const float* be2s = (const float*)d_in[12];
  const float* Wo   = (const float*)d_in[13];
  const float* bo   = (const float*)d_in[14];

  int N = in_sizes[0] / 64;  // 1048576
  int ntiles = N / 16;       // 65536
  float invN = 1.0f / (float)N;

  half8* bufT = (half8*)d_ws;                         // 64 MB f16 fragment buffer
  float* acc = (float*)(bufT + (size_t)ntiles * 64);  // 33 stages x 1024 floats

  hipMemsetAsync(acc, 0, 33 * STAGESZ * sizeof(float), stream);

  dim3 grid(NBLK), block(NT);
  const int HH = H * H;

  proj_kernel<<<grid, block, 0, stream>>>(x, Wp, bp, bufT, acc, ntiles);
  bn0_kernel<<<grid, block, 0, stream>>>(bufT, acc, acc + STAGESZ, g0, be0, W1s, b1s,
                                         ntiles, invN);

  for (int k = 0; k < 16; k++) {
    p2_kernel<<<grid, block, 0, stream>>>(
        bufT, acc + (size_t)(2 * k + 1) * STAGESZ, acc + (size_t)(2 * k + 2) * STAGESZ,
        g1s + k * H, be1s + k * H, W1s + k * HH, b1s + k * H,
        W2s + k * HH, b2s + k * H, ntiles, invN);
    if (k < 15) {
      p3_kernel<0><<<grid, block, 0, stream>>>(
          bufT, acc + (size_t)(2 * k + 1) * STAGESZ, acc + (size_t)(2 * k + 2) * STAGESZ,
          acc + (size_t)(2 * k + 3) * STAGESZ,
          g1s + k * H, be1s + k * H, g2s + k * H, be2s + k * H,
          W1s + k * HH, b1s + k * H, W2s + k * HH, b2s + k * H,
          W1s + (k + 1) * HH, b1s + (k + 1) * H, nullptr, nullptr, nullptr,
          ntiles, invN);
    } else {
      p3_kernel<1><<<grid, block, 0, stream>>>(
          bufT, acc + (size_t)(2 * k + 1) * STAGESZ, acc + (size_t)(2 * k + 2) * STAGESZ,
          nullptr,
          g1s + k * H, be1s + k * H, g2s + k * H, be2s + k * H,
          W1s + k * HH, b1s + k * H, W2s + k * HH, b2s + k * H,
          W1s + k * HH, b1s + k * H, Wo, bo, (float*)d_out, ntiles, invN);
    }
  }
}

// Round 19
// 826.408 us; speedup vs baseline: 1.0599x; 1.0599x over previous
//
#include <hip/hip_runtime.h>

#define H 22
#define EPS 1e-5f
#define SLOPE 0.01f
#define NT 256
#define NBLK 1024
#define WPB 4
#define NWAVES (NBLK * WPB)

// stats accumulators: 16 contention-split slots per stage.
// block b adds into slot (b & 15): su at [0..21], sq at [32..53].
#define NSLOT 16
#define SLOTSZ 64
#define STAGESZ (NSLOT * SLOTSZ)  // 1024 floats per stage

// packed bufT: per tile, 16 rows x 24 features fp16 = 768 B (was 1024 B).
// row n at fp16 offset t*384 + n*24; feature k at +k. k=22,23 stored as zeros.
#define TILE_F16 384

typedef __attribute__((ext_vector_type(8))) _Float16 half8;
typedef __attribute__((ext_vector_type(4))) _Float16 half4;
typedef __attribute__((ext_vector_type(4))) float f32x4;

#define MFMA(A, B, C) __builtin_amdgcn_mfma_f32_16x16x32_f16(A, B, C, 0, 0, 0)

__device__ __forceinline__ float leakyf(float u) { return u > 0.f ? u : SLOPE * u; }

// k/m mapping used CONSISTENTLY for all operand constructions:
// k(g,e) = 16*(e>>2) + 4*g + (e&3).  C-frag m at (tile,reg) = kmap(g, 4*tile+reg),
// so chained C->B repack is in-lane (validated rounds 8-18, absmax ~0.13).
__device__ __forceinline__ int kmap(int g, int e) {
  return ((e >> 2) << 4) + (g << 2) + (e & 3);
}

__device__ __forceinline__ half8 buildA(const float* __restrict__ W, int rows, int cols,
                                        int mbase, int kbase, int g) {
  int m = mbase + ((int)threadIdx.x & 15);
  half8 a;
#pragma unroll
  for (int e = 0; e < 8; e++) {
    int k = kbase + kmap(g, e);
    float v = (m < rows && k < cols) ? W[m * cols + k] : 0.f;
    a[e] = (_Float16)v;
  }
  return a;
}

// ---- packed tile I/O: lane (g,n) owns k = 4g..4g+3 (lo) and 16+4g..19+4g (hi, g<2)
__device__ __forceinline__ half8 load_tile(const _Float16* __restrict__ bufT,
                                           size_t t, int g, int n) {
  size_t base = t * TILE_F16 + (size_t)n * 24 + 4 * g;
  half4 lo = *(const half4*)(bufT + base);
  half8 r;
  r[0] = lo[0]; r[1] = lo[1]; r[2] = lo[2]; r[3] = lo[3];
  if (g < 2) {
    half4 hi = *(const half4*)(bufT + base + 16);
    r[4] = hi[0]; r[5] = hi[1]; r[6] = hi[2]; r[7] = hi[3];
  } else {
    r[4] = (_Float16)0.f; r[5] = (_Float16)0.f;
    r[6] = (_Float16)0.f; r[7] = (_Float16)0.f;
  }
  return r;
}

__device__ __forceinline__ void store_tile(_Float16* __restrict__ bufT,
                                           size_t t, int g, int n, half8 v) {
  size_t base = t * TILE_F16 + (size_t)n * 24 + 4 * g;
  half4 lo = {v[0], v[1], v[2], v[3]};
  *(half4*)(bufT + base) = lo;
  if (g < 2) {
    half4 hi = {v[4], v[5], v[6], v[7]};
    *(half4*)(bufT + base + 16) = hi;
  }
}

// sum the 16 slots of a stage for feature t (t < H)
__device__ __forceinline__ void read_stats(const float* __restrict__ accStage,
                                           int t, float& su, float& sq) {
  su = 0.f; sq = 0.f;
#pragma unroll
  for (int sI = 0; sI < NSLOT; sI++) {
    su += accStage[sI * SLOTSZ + t];
    sq += accStage[sI * SLOTSZ + 32 + t];
  }
}

// per-wave stats -> block reduce -> 44 atomics into this block's slot
__device__ __forceinline__ void commit_stats(float* s, float* q,
                                             float red[WPB][2 * H],
                                             float* __restrict__ accStage) {
  int lane = (int)threadIdx.x & 63, w = (int)threadIdx.x >> 6, g = lane >> 4;
#pragma unroll
  for (int r = 0; r < 8; r++) {
#pragma unroll
    for (int off = 1; off < 16; off <<= 1) {
      s[r] += __shfl_xor(s[r], off);
      q[r] += __shfl_xor(q[r], off);
    }
  }
  if ((lane & 15) == 0) {
#pragma unroll
    for (int r = 0; r < 8; r++) {
      int m = kmap(g, r);
      if (m < H) { red[w][m] = s[r]; red[w][H + m] = q[r]; }
    }
  }
  __syncthreads();
  int tid = threadIdx.x;
  if (tid < 2 * H) {
    float v = red[0][tid] + red[1][tid] + red[2][tid] + red[3][tid];
    float* slot = accStage + (blockIdx.x & (NSLOT - 1)) * SLOTSZ;
    int off = (tid < H) ? tid : (32 + tid - H);
    atomicAdd(&slot[off], v);
  }
}

// ---- proj: z0 = Wp @ x + bp -> bufT (packed), stats(z0) -> stage 0
__global__ void __launch_bounds__(NT) proj_kernel(
    const float* __restrict__ x, const float* __restrict__ Wp,
    const float* __restrict__ bp, _Float16* __restrict__ bufT,
    float* __restrict__ acc0, int ntiles) {
  __shared__ float sBP[32];
  __shared__ float red[WPB][2 * H];
  int tid = threadIdx.x;
  if (tid < 32) sBP[tid] = (tid < H) ? bp[tid] : 0.f;
  __syncthreads();
  int lane = tid & 63, w = tid >> 6, g = lane >> 4, n = lane & 15;
  int wid = blockIdx.x * WPB + w;

  half8 A00 = buildA(Wp, H, 64, 0, 0, g);
  half8 A01 = buildA(Wp, H, 64, 0, 32, g);
  half8 A10 = buildA(Wp, H, 64, 16, 0, g);
  half8 A11 = buildA(Wp, H, 64, 16, 32, g);
  float bpv[8];
#pragma unroll
  for (int e = 0; e < 8; e++) bpv[e] = sBP[kmap(g, e)];

  float s[8], q[8];
#pragma unroll
  for (int e = 0; e < 8; e++) { s[e] = 0.f; q[e] = 0.f; }

  const float4* x4 = (const float4*)x;
  for (int t = wid; t < ntiles; t += NWAVES) {
    size_t row = (size_t)t * 16 + n;
    float4 lo0 = x4[row * 16 + g];        // k = 4g..4g+3
    float4 hi0 = x4[row * 16 + 4 + g];    // k = 16+4g..
    float4 lo1 = x4[row * 16 + 8 + g];    // k = 32+4g..
    float4 hi1 = x4[row * 16 + 12 + g];   // k = 48+4g..
    half8 B0, B1;
    B0[0] = (_Float16)lo0.x; B0[1] = (_Float16)lo0.y;
    B0[2] = (_Float16)lo0.z; B0[3] = (_Float16)lo0.w;
    B0[4] = (_Float16)hi0.x; B0[5] = (_Float16)hi0.y;
    B0[6] = (_Float16)hi0.z; B0[7] = (_Float16)hi0.w;
    B1[0] = (_Float16)lo1.x; B1[1] = (_Float16)lo1.y;
    B1[2] = (_Float16)lo1.z; B1[3] = (_Float16)lo1.w;
    B1[4] = (_Float16)hi1.x; B1[5] = (_Float16)hi1.y;
    B1[6] = (_Float16)hi1.z; B1[7] = (_Float16)hi1.w;

    f32x4 c0 = {0.f, 0.f, 0.f, 0.f}, c1 = {0.f, 0.f, 0.f, 0.f};
    c0 = MFMA(A00, B0, c0); c0 = MFMA(A01, B1, c0);
    c1 = MFMA(A10, B0, c1); c1 = MFMA(A11, B1, c1);

    half8 zb;
#pragma unroll
    for (int e = 0; e < 8; e++) {
      float z = ((e < 4) ? c0[e & 3] : c1[e & 3]) + bpv[e];  // m>=22: A rows 0, bpv 0 -> z=0
      s[e] += z; q[e] += z * z;
      zb[e] = (_Float16)z;
    }
    store_tile(bufT, (size_t)t, g, n, zb);
  }
  commit_stats(s, q, red, acc0);
}

// ---- bn0: h0 = a0*z0 + c0 (in place) ; stats of z1_0 = W1 h0 + b1
__global__ void __launch_bounds__(NT) bn0_kernel(
    _Float16* __restrict__ bufT, const float* __restrict__ accIn,
    float* __restrict__ accOut, const float* __restrict__ g0,
    const float* __restrict__ be0, const float* __restrict__ W1,
    const float* __restrict__ b1, int ntiles, float invN) {
  __shared__ float sA[32], sC[32], sB1[32];
  __shared__ float red[WPB][2 * H];
  int tid = threadIdx.x;
  if (tid < 32) {
    float a = 0.f, c = 0.f, bv = 0.f;
    if (tid < H) {
      float su, sq; read_stats(accIn, tid, su, sq);
      float mu = su * invN;
      float var = sq * invN - mu * mu;
      a = g0[tid] * rsqrtf(var + EPS);
      c = be0[tid] - a * mu;
      bv = b1[tid];
    }
    sA[tid] = a; sC[tid] = c; sB1[tid] = bv;
  }
  __syncthreads();
  int lane = tid & 63, w = tid >> 6, g = lane >> 4, n = lane & 15;
  int wid = blockIdx.x * WPB + w;

  half8 A0 = buildA(W1, H, H, 0, 0, g), A1 = buildA(W1, H, H, 16, 0, g);
  float aK[8], cK[8], b1v[8];
#pragma unroll
  for (int e = 0; e < 8; e++) {
    int m = kmap(g, e);
    aK[e] = sA[m]; cK[e] = sC[m]; b1v[e] = sB1[m];
  }
  float s[8], q[8];
#pragma unroll
  for (int e = 0; e < 8; e++) { s[e] = 0.f; q[e] = 0.f; }

  for (int t = wid; t < ntiles; t += NWAVES) {
    half8 zb = load_tile(bufT, (size_t)t, g, n);
    half8 hb;
#pragma unroll
    for (int e = 0; e < 8; e++)
      hb[e] = (_Float16)(aK[e] * (float)zb[e] + cK[e]);   // pad features: aK=cK=0 -> 0
    store_tile(bufT, (size_t)t, g, n, hb);
    f32x4 c0 = {0.f, 0.f, 0.f, 0.f}, c1 = {0.f, 0.f, 0.f, 0.f};
    c0 = MFMA(A0, hb, c0);
    c1 = MFMA(A1, hb, c1);
#pragma unroll
    for (int e = 0; e < 8; e++) {
      float z = ((e < 4) ? c0[e & 3] : c1[e & 3]) + b1v[e];
      s[e] += z; q[e] += z * z;
    }
  }
  commit_stats(s, q, red, accOut);
}

// ---- P2: t = leaky(a1*(W1 h) + b1f) ; z2 = W2 t + b2 (raw) ; stats(z2)
__global__ void __launch_bounds__(NT) p2_kernel(
    const _Float16* __restrict__ bufT, const float* __restrict__ accIn,
    float* __restrict__ accOut, const float* __restrict__ g1,
    const float* __restrict__ be1, const float* __restrict__ W1,
    const float* __restrict__ b1, const float* __restrict__ W2,
    const float* __restrict__ b2, int ntiles, float invN) {
  __shared__ float sA1[32], sB1F[32], sB2[32];
  __shared__ float red[WPB][2 * H];
  int tid = threadIdx.x;
  if (tid < 32) {
    float a = 0.f, bf = 0.f, bv = 0.f;
    if (tid < H) {
      float su, sq; read_stats(accIn, tid, su, sq);
      float mu = su * invN;
      float var = sq * invN - mu * mu;
      a = g1[tid] * rsqrtf(var + EPS);
      bf = a * b1[tid] + be1[tid] - a * mu;
      bv = b2[tid];
    }
    sA1[tid] = a; sB1F[tid] = bf; sB2[tid] = bv;
  }
  __syncthreads();
  int lane = tid & 63, w = tid >> 6, g = lane >> 4, n = lane & 15;
  int wid = blockIdx.x * WPB + w;

  half8 A10 = buildA(W1, H, H, 0, 0, g), A11 = buildA(W1, H, H, 16, 0, g);
  half8 A20 = buildA(W2, H, H, 0, 0, g), A21 = buildA(W2, H, H, 16, 0, g);
  float a1v[8], b1v[8], b2v[8];
#pragma unroll
  for (int e = 0; e < 8; e++) {
    int m = kmap(g, e);
    a1v[e] = sA1[m]; b1v[e] = sB1F[m]; b2v[e] = sB2[m];
  }
  float s[8], q[8];
#pragma unroll
  for (int e = 0; e < 8; e++) { s[e] = 0.f; q[e] = 0.f; }

  for (int t = wid; t < ntiles; t += NWAVES) {
    half8 hb = load_tile(bufT, (size_t)t, g, n);
    f32x4 c0 = {0.f, 0.f, 0.f, 0.f}, c1 = {0.f, 0.f, 0.f, 0.f};
    c0 = MFMA(A10, hb, c0);
    c1 = MFMA(A11, hb, c1);
    half8 tb;
#pragma unroll
    for (int e = 0; e < 8; e++) {
      float c = (e < 4) ? c0[e & 3] : c1[e & 3];
      tb[e] = (_Float16)leakyf(a1v[e] * c + b1v[e]);      // pad: a1v=b1v=0 -> 0
    }
    f32x4 d0 = {0.f, 0.f, 0.f, 0.f}, d1 = {0.f, 0.f, 0.f, 0.f};
    d0 = MFMA(A20, tb, d0);
    d1 = MFMA(A21, tb, d1);
#pragma unroll
    for (int e = 0; e < 8; e++) {
      float z = ((e < 4) ? d0[e & 3] : d1[e & 3]) + b2v[e];
      s[e] += z; q[e] += z * z;
    }
  }
  commit_stats(s, q, red, accOut);
}

// ---- P3: recompute t, z2 ; h' = leaky(h + a2*(W2 t) + b2f) ; store h' ;
//          fused next-layer z1 stats (raw) or final output when LAST
template <int LAST>
__global__ void __launch_bounds__(NT) p3_kernel(
    _Float16* __restrict__ bufT, const float* __restrict__ accZ1,
    const float* __restrict__ accZ2, float* __restrict__ accOut,
    const float* __restrict__ g1, const float* __restrict__ be1,
    const float* __restrict__ g2, const float* __restrict__ be2,
    const float* __restrict__ W1, const float* __restrict__ b1,
    const float* __restrict__ W2, const float* __restrict__ b2,
    const float* __restrict__ W1n, const float* __restrict__ b1n,
    const float* __restrict__ Wo, const float* __restrict__ bo,
    float* __restrict__ out, int ntiles, float invN) {
  __shared__ float sA1[32], sB1F[32], sA2[32], sB2F[32], sAux[32];
  __shared__ float red[WPB][2 * H];
  int tid = threadIdx.x;
  if (tid < 32) {
    float a1 = 0.f, b1f = 0.f, a2 = 0.f, b2f = 0.f, aux = 0.f;
    if (tid < H) {
      float su1, sq1; read_stats(accZ1, tid, su1, sq1);
      float mu1 = su1 * invN;
      float v1 = sq1 * invN - mu1 * mu1;
      a1 = g1[tid] * rsqrtf(v1 + EPS);
      b1f = a1 * b1[tid] + be1[tid] - a1 * mu1;
      float su2, sq2; read_stats(accZ2, tid, su2, sq2);
      float mu2 = su2 * invN;
      float v2 = sq2 * invN - mu2 * mu2;
      a2 = g2[tid] * rsqrtf(v2 + EPS);
      b2f = a2 * b2[tid] + be2[tid] - a2 * mu2;
      aux = LAST ? Wo[tid] : b1n[tid];
    }
    sA1[tid] = a1; sB1F[tid] = b1f; sA2[tid] = a2; sB2F[tid] = b2f; sAux[tid] = aux;
  }
  __syncthreads();
  int lane = tid & 63, w = tid >> 6, g = lane >> 4, n = lane & 15;
  int wid = blockIdx.x * WPB + w;

  half8 A10 = buildA(W1, H, H, 0, 0, g), A11 = buildA(W1, H, H, 16, 0, g);
  half8 A20 = buildA(W2, H, H, 0, 0, g), A21 = buildA(W2, H, H, 16, 0, g);
  half8 An0 = {}, An1 = {};
  if (!LAST) { An0 = buildA(W1n, H, H, 0, 0, g); An1 = buildA(W1n, H, H, 16, 0, g); }
  float a1v[8], b1v[8], a2v[8], b2v[8], auxv[8];
#pragma unroll
  for (int e = 0; e < 8; e++) {
    int m = kmap(g, e);
    a1v[e] = sA1[m]; b1v[e] = sB1F[m]; a2v[e] = sA2[m]; b2v[e] = sB2F[m]; auxv[e] = sAux[m];
  }
  float s[8], q[8];
#pragma unroll
  for (int e = 0; e < 8; e++) { s[e] = 0.f; q[e] = 0.f; }
  float bo0 = LAST ? bo[0] : 0.f;

  for (int t = wid; t < ntiles; t += NWAVES) {
    half8 hb = load_tile(bufT, (size_t)t, g, n);
    f32x4 c0 = {0.f, 0.f, 0.f, 0.f}, c1 = {0.f, 0.f, 0.f, 0.f};
    c0 = MFMA(A10, hb, c0);
    c1 = MFMA(A11, hb, c1);
    half8 tb;
#pragma unroll
    for (int e = 0; e < 8; e++) {
      float c = (e < 4) ? c0[e & 3] : c1[e & 3];
      tb[e] = (_Float16)leakyf(a1v[e] * c + b1v[e]);
    }
    f32x4 d0 = {0.f, 0.f, 0.f, 0.f}, d1 = {0.f, 0.f, 0.f, 0.f};
    d0 = MFMA(A20, tb, d0);
    d1 = MFMA(A21, tb, d1);
    float hn[8];
    half8 nb;
#pragma unroll
    for (int e = 0; e < 8; e++) {
      float d = (e < 4) ? d0[e & 3] : d1[e & 3];
      // residual: C-frag m at (tile,reg)=e equals B-elem feature kmap(g,e) -> same lane/elem
      float hv = (float)hb[e];
      hn[e] = leakyf(hv + a2v[e] * d + b2v[e]);            // pad: a2v=b2v=0, hv=0 -> 0
      nb[e] = (_Float16)hn[e];
    }
    if (!LAST) {
      store_tile(bufT, (size_t)t, g, n, nb);
      f32x4 e0 = {0.f, 0.f, 0.f, 0.f}, e1 = {0.f, 0.f, 0.f, 0.f};
      e0 = MFMA(An0, nb, e0);
      e1 = MFMA(An1, nb, e1);
#pragma unroll
      for (int e = 0; e < 8; e++) {
        float z = ((e < 4) ? e0[e & 3] : e1[e & 3]) + auxv[e];
        s[e] += z; q[e] += z * z;
      }
    } else {
      float part = 0.f;
#pragma unroll
      for (int e = 0; e < 8; e++) part += auxv[e] * hn[e];
      part += __shfl_xor(part, 16);
      part += __shfl_xor(part, 32);
      if (lane < 16) out[(size_t)t * 16 + n] = part + bo0;
    }
  }
  if (!LAST) commit_stats(s, q, red, accOut);
}

extern "C" void kernel_launch(void* const* d_in, const int* in_sizes, int n_in,
                              void* d_out, int out_size, void* d_ws, size_t ws_size,
                              hipStream_t stream) {
  const float* x    = (const float*)d_in[0];
  const float* Wp   = (const float*)d_in[1];
  const float* bp   = (const float*)d_in[2];
  const float* g0   = (const float*)d_in[3];
  const float* be0  = (const float*)d_in[4];
  const float* W1s  = (const float*)d_in[5];
  const float* b1s  = (const float*)d_in[6];
  const float* g1s  = (const float*)d_in[7];
  const float* be1s = (const float*)d_in[8];
  const float* W2s  = (const float*)d_in[9];
  const float* b2s  = (const float*)d_in[10];
  const float* g2s  = (const float*)d_in[11];
  const float* be2s = (const float*)d_in[12];
  const float* Wo   = (const float*)d_in[13];
  const float* bo   = (const float*)d_in[14];

  int N = in_sizes[0] / 64;  // 1048576
  int ntiles = N / 16;       // 65536
  float invN = 1.0f / (float)N;

  _Float16* bufT = (_Float16*)d_ws;                          // 48 MB packed buffer
  float* acc = (float*)(bufT + (size_t)ntiles * TILE_F16);   // 33 stages x 1024 floats

  hipMemsetAsync(acc, 0, 33 * STAGESZ * sizeof(float), stream);

  dim3 grid(NBLK), block(NT);
  const int HH = H * H;

  proj_kernel<<<grid, block, 0, stream>>>(x, Wp, bp, bufT, acc, ntiles);
  bn0_kernel<<<grid, block, 0, stream>>>(bufT, acc, acc + STAGESZ, g0, be0, W1s, b1s,
                                         ntiles, invN);

  for (int k = 0; k < 16; k++) {
    p2_kernel<<<grid, block, 0, stream>>>(
        bufT, acc + (size_t)(2 * k + 1) * STAGESZ, acc + (size_t)(2 * k + 2) * STAGESZ,
        g1s + k * H, be1s + k * H, W1s + k * HH, b1s + k * H,
        W2s + k * HH, b2s + k * H, ntiles, invN);
    if (k < 15) {
      p3_kernel<0><<<grid, block, 0, stream>>>(
          bufT, acc + (size_t)(2 * k + 1) * STAGESZ, acc + (size_t)(2 * k + 2) * STAGESZ,
          acc + (size_t)(2 * k + 3) * STAGESZ,
          g1s + k * H, be1s + k * H, g2s + k * H, be2s + k * H,
          W1s + k * HH, b1s + k * H, W2s + k * HH, b2s + k * H,
          W1s + (k + 1) * HH, b1s + (k + 1) * H, nullptr, nullptr, nullptr,
          ntiles, invN);
    } else {
      p3_kernel<1><<<grid, block, 0, stream>>>(
          bufT, acc + (size_t)(2 * k + 1) * STAGESZ, acc + (size_t)(2 * k + 2) * STAGESZ,
          nullptr,
          g1s + k * H, be1s + k * H, g2s + k * H, be2s + k * H,
          W1s + k * HH, b1s + k * H, W2s + k * HH, b2s + k * H,
          W1s + k * HH, b1s + k * H, Wo, bo, (float*)d_out, ntiles, invN);
    }
  }
}